// Round 14
// baseline (323.886 us; speedup 1.0000x reference)
//
#include <hip/hip_runtime.h>
#include <hip/hip_bf16.h>

#define NTOK 49
#define DIM 256
#define HEADS 8
#define HD 32
#define SCALE 0.17677669529663687f

typedef float f32x4 __attribute__((ext_vector_type(4)));
typedef short bf16x8 __attribute__((ext_vector_type(8)));
typedef short bf16x4 __attribute__((ext_vector_type(4)));

__device__ __forceinline__ unsigned short f2bf(float f) {
    union { __hip_bfloat16 h; unsigned short u; } c;
    c.h = __float2bfloat16(f);
    return c.u;
}
__device__ __forceinline__ float bf2f(unsigned short u) {
    return __builtin_bit_cast(float, (unsigned)u << 16);
}
__device__ __forceinline__ uint2 pack4(float a, float b, float c, float d) {
    uint2 r;
    r.x = (unsigned)f2bf(a) | ((unsigned)f2bf(b) << 16);
    r.y = (unsigned)f2bf(c) | ((unsigned)f2bf(d) << 16);
    return r;
}

// K=16 bf16 MFMA on packed uint2 fragments (4 bf16/lane, k = (lane>>4)*4+j).
// Its A/B fragment layout coincides with the 16x16x32 D-fragment layout.
__device__ __forceinline__ f32x4 mfma16(uint2 a, uint2 b, f32x4 c) {
    bf16x4 av = __builtin_bit_cast(bf16x4, a);
    bf16x4 bv = __builtin_bit_cast(bf16x4, b);
#if __has_builtin(__builtin_amdgcn_mfma_f32_16x16x16bf16_1k)
    return __builtin_amdgcn_mfma_f32_16x16x16bf16_1k(av, bv, c, 0, 0, 0);
#elif __has_builtin(__builtin_amdgcn_mfma_f32_16x16x16_bf16)
    return __builtin_amdgcn_mfma_f32_16x16x16_bf16(av, bv, c, 0, 0, 0);
#else
    f32x4 d;
    asm volatile("v_mfma_f32_16x16x16_bf16 %0, %1, %2, %3"
                 : "=v"(d) : "v"(av), "v"(bv), "v"(c));
    return d;
#endif
}

// ---------------------------------------------------------------------------
// K0: one-time prep into d_ws (byte-identical to rounds 8/9/12/13):
//   wqf [196608] bf16 : qkv_w in MFMA fragment order
//   wpf [65536]  bf16 : proj_w in MFMA fragment order
//   bmf [2097152] bf16 : mask+bias in S^T D-fragment order
//       idx = ((ws*8+h)*16 + ct*4 + mt)*256 + lane*4 + j
//       -> (query q = ct*16 + (lane&15), key = mt*16 + (lane>>4)*4 + j)
// ---------------------------------------------------------------------------
__global__ void k0_prep(const float* __restrict__ qkv_w, const float* __restrict__ proj_w,
                        const float* __restrict__ mask, const float* __restrict__ bias_table,
                        const int* __restrict__ rel_idx,
                        unsigned short* __restrict__ wqf, unsigned short* __restrict__ wpf,
                        unsigned short* __restrict__ bmf, int total)
{
    int i = blockIdx.x * 256 + threadIdx.x;
    if (i >= total) return;
    if (i < 196608) {
        int j = i & 7, q = i >> 3;
        int lane = q & 63; q >>= 6;
        int ks2 = q & 7;  q >>= 3;
        int tt = q % 6;   q /= 6;
        int h  = q;
        int n96 = tt * 16 + (lane & 15);
        int seg = n96 >> 5, ch = n96 & 31;
        wqf[i] = f2bf(qkv_w[(seg * 256 + h * HD + ch) * 256 + ks2 * 32 + (lane >> 4) * 8 + j]);
    } else if (i < 262144) {
        int u = i - 196608;
        int j = u & 7, q = u >> 3;
        int lane = q & 63; q >>= 6;
        int ks2 = q & 7;  q >>= 3;
        int bt = q;                       // 0..15
        int n = (bt >> 3) * 128 + (bt & 7) * 16 + (lane & 15);
        wpf[u] = f2bf(proj_w[n * 256 + ks2 * 32 + (lane >> 4) * 8 + j]);
    } else {
        int u = i - 262144;               // [0, 2097152)
        int j = u & 3;
        int lane = (u >> 2) & 63;
        int g = u >> 8;                   // ws*128 + h*16 + ct*4 + mt
        int mt = g & 3, ct = (g >> 2) & 3, h = (g >> 4) & 7, ws = g >> 7;
        int q = ct * 16 + (lane & 15);
        int key = mt * 16 + ((lane >> 4) & 3) * 4 + j;
        float v = 0.f;
        if (q < NTOK && key < NTOK)
            v = mask[ws * 2401 + q * NTOK + key] + bias_table[rel_idx[q * NTOK + key] * HEADS + h];
        bmf[u] = f2bf(v);
    }
}

// ---------------------------------------------------------------------------
// K1: fully fused qkv + attention + proj. 4096 blocks x 256 threads (4 waves).
// Wave wv owns heads {wv, wv+4}. Attention fully REGISTER-resident (q/k/v/P
// never touch LDS; 16x16x16 MFMAs consume 16x16x32 D-frags directly).
// Round-13 kernel (passed, 238us) with ONE change: __launch_bounds__ REMOVED.
// Measured r4-r13: the 2nd launch_bounds arg acts as a hard blocks/CU target
// (a=2 -> VGPR cap 128 but only ~2 blocks/CU resident = 8 waves/CU, 22.5%
// occupancy). Default waves-per-eu (4,10) keeps the 128-VGPR budget (live set
// ~111, no spill) but lets the HW co-schedule up to 5 blocks/CU
// (VGPR 100 -> 5 waves/SIMD; LDS 25088 allows 6). 3 barriers/block.
// Streaming accesses (x read-once, out write-once) stay NON-TEMPORAL so the
// L2 keeps wqf/wpf/bmf hot (r13: -25 MB FETCH, +22 us).
// ---------------------------------------------------------------------------
__global__ void k1_fused(
    const float* __restrict__ x,             // [4096,49,256] f32
    const float* __restrict__ qkv_b,         // [768] f32
    const float* __restrict__ pb,            // [256] f32
    const unsigned short* __restrict__ wqf,  // fragment-ordered qkv_w bf16
    const unsigned short* __restrict__ wpf,  // fragment-ordered proj_w bf16
    const unsigned short* __restrict__ bmf,  // fragment-ordered mask+bias bf16
    float* __restrict__ out)                 // [4096,49,256] f32 final
{
    __shared__ unsigned short xs[49 * 256];  // 25088 B (x; reused for ao)

    const int t = threadIdx.x, bw = blockIdx.x;
    const int lane = t & 63, wv = t >> 6;
    const int l15 = lane & 15, l16 = lane >> 4;

    // ---- stage x rows 0..48 -> bf16 LDS (XOR swizzle; NON-TEMPORAL reads)
    const float* xw = x + (size_t)bw * NTOK * DIM;
    for (int cidx = t; cidx < NTOK * 32; cidx += 256) {
        int row = cidx >> 5, c8 = cidx & 31;
        f32x4 a = __builtin_nontemporal_load((const f32x4*)(xw + row * DIM + c8 * 8));
        f32x4 b = __builtin_nontemporal_load((const f32x4*)(xw + row * DIM + c8 * 8 + 4));
        bf16x8 v;
        v[0] = (short)f2bf(a[0]); v[1] = (short)f2bf(a[1]);
        v[2] = (short)f2bf(a[2]); v[3] = (short)f2bf(a[3]);
        v[4] = (short)f2bf(b[0]); v[5] = (short)f2bf(b[1]);
        v[6] = (short)f2bf(b[2]); v[7] = (short)f2bf(b[3]);
        *(bf16x8*)(xs + row * 256 + ((c8 * 8) ^ ((row & 7) << 3))) = v;
    }
    __syncthreads();   // barrier 1: xs ready

    int arow[4];
    #pragma unroll
    for (int i4 = 0; i4 < 4; ++i4) {
        int r = i4 * 16 + l15;
        arow[i4] = r > 48 ? 48 : r;     // row clamp (49 real rows in xs)
    }

    uint2 ob[2][2][4];                  // packed bf16 out^T frags [hh][a][ct]

    #pragma unroll
    for (int hh = 0; hh < 2; ++hh) {
        const int h = wv + 4 * hh;
        const unsigned short* wb = wqf + (size_t)h * 24576;
        uint2 qpk[4][2], kpk[4][2], vpk[4][2];   // [tok-tile][ch-chunk p]
        uint2 bmu[4][4];                         // [ct][mt] bias+mask frags

        // ---------- qkv: 2 passes of 16x16x32; outputs stay in registers ----
        #pragma unroll
        for (int p = 0; p < 2; ++p) {
            f32x4 aq[4], ak[4], av[4];
            #pragma unroll
            for (int nt = 0; nt < 4; ++nt) {
                aq[nt] = (f32x4){0.f,0.f,0.f,0.f};
                ak[nt] = (f32x4){0.f,0.f,0.f,0.f};
                av[nt] = (f32x4){0.f,0.f,0.f,0.f};
            }
            __builtin_amdgcn_s_setprio(1);
            #pragma unroll
            for (int ks2 = 0; ks2 < 8; ++ks2) {
                bf16x8 xf[4];
                #pragma unroll
                for (int nt = 0; nt < 4; ++nt)
                    xf[nt] = *(const bf16x8*)(xs + arow[nt] * 256 +
                               ((ks2 * 32 + l16 * 8) ^ ((arow[nt] & 7) << 3)));
                bf16x8 wqf_ = *(const bf16x8*)(wb + ((p    ) * 8 + ks2) * 512 + lane * 8);
                bf16x8 wkf_ = *(const bf16x8*)(wb + ((2 + p) * 8 + ks2) * 512 + lane * 8);
                bf16x8 wvf_ = *(const bf16x8*)(wb + ((4 + p) * 8 + ks2) * 512 + lane * 8);
                #pragma unroll
                for (int nt = 0; nt < 4; ++nt) {
                    aq[nt] = __builtin_amdgcn_mfma_f32_16x16x32_bf16(wqf_, xf[nt], aq[nt], 0, 0, 0);
                    ak[nt] = __builtin_amdgcn_mfma_f32_16x16x32_bf16(wkf_, xf[nt], ak[nt], 0, 0, 0);
                    av[nt] = __builtin_amdgcn_mfma_f32_16x16x32_bf16(xf[nt], wvf_, av[nt], 0, 0, 0);
                }
            }
            __builtin_amdgcn_s_setprio(0);

            if (p == 1) {   // prefetch softmax bias+mask (hidden by epilogue)
                #pragma unroll
                for (int ct = 0; ct < 4; ++ct)
                    #pragma unroll
                    for (int mt = 0; mt < 4; ++mt)
                        bmu[ct][mt] = *(const uint2*)(bmf +
                            (((size_t)(((bw & 63) * 8 + h) * 16 + ct * 4 + mt)) << 8) + (lane << 2));
            }

            // epilogue: bias + pack into MFMA-K16-ready register fragments
            float4 bq4 = *(const float4*)(qkv_b + h * HD + p * 16 + l16 * 4);
            float4 bk4 = *(const float4*)(qkv_b + 256 + h * HD + p * 16 + l16 * 4);
            float  bvs = qkv_b[512 + h * HD + p * 16 + l15];
            #pragma unroll
            for (int nt = 0; nt < 4; ++nt) {
                qpk[nt][p] = pack4((aq[nt][0] + bq4.x) * SCALE, (aq[nt][1] + bq4.y) * SCALE,
                                   (aq[nt][2] + bq4.z) * SCALE, (aq[nt][3] + bq4.w) * SCALE);
                kpk[nt][p] = pack4(ak[nt][0] + bk4.x, ak[nt][1] + bk4.y,
                                   ak[nt][2] + bk4.z, ak[nt][3] + bk4.w);
                vpk[nt][p] = pack4(av[nt][0] + bvs, av[nt][1] + bvs,
                                   av[nt][2] + bvs, av[nt][3] + bvs);
            }
        }

        // ---------- per q-tile ct: S^T (reg) + softmax + PV (reg) ----------
        #pragma unroll
        for (int ct = 0; ct < 4; ++ct) {
            f32x4 sT[4];
            __builtin_amdgcn_s_setprio(1);
            #pragma unroll
            for (int mt = 0; mt < 4; ++mt) {
                f32x4 z = (f32x4){0.f,0.f,0.f,0.f};
                sT[mt] = mfma16(kpk[mt][1], qpk[ct][1],
                                mfma16(kpk[mt][0], qpk[ct][0], z));
            }
            __builtin_amdgcn_s_setprio(0);

            float vv[4][4];
            float mx = -1e30f;
            #pragma unroll
            for (int mt = 0; mt < 4; ++mt) {
                float b0 = bf2f((unsigned short)(bmu[ct][mt].x & 0xffff));
                float b1 = bf2f((unsigned short)(bmu[ct][mt].x >> 16));
                float b2 = bf2f((unsigned short)(bmu[ct][mt].y & 0xffff));
                float b3 = bf2f((unsigned short)(bmu[ct][mt].y >> 16));
                float bj[4] = {b0, b1, b2, b3};
                #pragma unroll
                for (int j = 0; j < 4; ++j) {
                    float v = sT[mt][j] + bj[j];
                    if (mt * 16 + l16 * 4 + j >= NTOK) v = -1e30f;  // key mask
                    vv[mt][j] = v;
                    mx = fmaxf(mx, v);
                }
            }
            mx = fmaxf(mx, __shfl_xor(mx, 16));
            mx = fmaxf(mx, __shfl_xor(mx, 32));
            float sum = 0.f;
            #pragma unroll
            for (int mt = 0; mt < 4; ++mt)
                #pragma unroll
                for (int j = 0; j < 4; ++j) {
                    float e = __expf(vv[mt][j] - mx);
                    vv[mt][j] = e;
                    sum += e;
                }
            sum += __shfl_xor(sum, 16);
            sum += __shfl_xor(sum, 32);
            float inv = 1.f / sum;

            uint2 ppk[4];
            #pragma unroll
            for (int mt = 0; mt < 4; ++mt)
                ppk[mt] = pack4(vv[mt][0] * inv, vv[mt][1] * inv,
                                vv[mt][2] * inv, vv[mt][3] * inv);

            f32x4 o0 = (f32x4){0.f,0.f,0.f,0.f};
            f32x4 o1 = (f32x4){0.f,0.f,0.f,0.f};
            __builtin_amdgcn_s_setprio(1);
            #pragma unroll
            for (int mt = 0; mt < 4; ++mt) {
                o0 = mfma16(vpk[mt][0], ppk[mt], o0);
                o1 = mfma16(vpk[mt][1], ppk[mt], o1);
            }
            __builtin_amdgcn_s_setprio(0);
            ob[hh][0][ct] = pack4(o0[0], o0[1], o0[2], o0[3]);
            ob[hh][1][ct] = pack4(o1[0], o1[1], o1[2], o1[3]);
        }
    }

    __syncthreads();   // barrier 2: all waves past their last xs read

    // ---- scatter attention output (both heads) into xs as bf16, b64 stores
    #pragma unroll
    for (int hh = 0; hh < 2; ++hh) {
        #pragma unroll
        for (int a = 0; a < 2; ++a) {
            #pragma unroll
            for (int ct = 0; ct < 4; ++ct) {
                int tok = ct * 16 + l15;
                if (tok < NTOK) {
                    int ch0 = (wv + 4 * hh) * HD + a * 16 + l16 * 4;
                    int ad = tok * 256 + ((ch0 & ~7) ^ ((tok & 7) << 3)) + (ch0 & 7);
                    *(uint2*)(xs + ad) = ob[hh][a][ct];
                }
            }
        }
    }
    __syncthreads();   // barrier 3: ao ready in xs

    // ---- proj (swapped): D col=tok -> float4 NT stores. Wave: 4 col-tiles.
    f32x4 pacc[4][4];   // [ct][u]
    #pragma unroll
    for (int ct = 0; ct < 4; ++ct)
        #pragma unroll
        for (int u = 0; u < 4; ++u) pacc[ct][u] = (f32x4){0.f,0.f,0.f,0.f};

    __builtin_amdgcn_s_setprio(1);
    #pragma unroll
    for (int ks2 = 0; ks2 < 8; ++ks2) {
        bf16x8 xf[4];
        #pragma unroll
        for (int ct = 0; ct < 4; ++ct)
            xf[ct] = *(const bf16x8*)(xs + arow[ct] * 256 +
                       ((ks2 * 32 + l16 * 8) ^ ((arow[ct] & 7) << 3)));
        #pragma unroll
        for (int u = 0; u < 4; ++u) {
            bf16x8 wf = *(const bf16x8*)(wpf + (size_t)((wv * 4 + u) * 8 + ks2) * 512 + lane * 8);
            #pragma unroll
            for (int ct = 0; ct < 4; ++ct)
                pacc[ct][u] = __builtin_amdgcn_mfma_f32_16x16x32_bf16(wf, xf[ct], pacc[ct][u], 0, 0, 0);
        }
    }
    __builtin_amdgcn_s_setprio(0);

    #pragma unroll
    for (int u = 0; u < 4; ++u) {
        int bt = wv * 4 + u;
        int base = (bt >> 3) * 128 + (bt & 7) * 16;
        float4 pb4 = *(const float4*)(pb + base + l16 * 4);
        #pragma unroll
        for (int ct = 0; ct < 4; ++ct) {
            int tok = ct * 16 + l15;
            if (tok < NTOK) {
                f32x4 r;
                r[0] = pacc[ct][u][0] + pb4.x;
                r[1] = pacc[ct][u][1] + pb4.y;
                r[2] = pacc[ct][u][2] + pb4.z;
                r[3] = pacc[ct][u][3] + pb4.w;
                __builtin_nontemporal_store(r,
                    (f32x4*)(out + ((size_t)bw * NTOK + tok) * DIM + base + l16 * 4));
            }
        }
    }
}

extern "C" void kernel_launch(void* const* d_in, const int* in_sizes, int n_in,
                              void* d_out, int out_size, void* d_ws, size_t ws_size,
                              hipStream_t stream) {
    const float* x    = (const float*)d_in[0];
    const float* mask = (const float*)d_in[1];
    const float* qkvw = (const float*)d_in[2];
    const float* qkvb = (const float*)d_in[3];
    const float* pw   = (const float*)d_in[4];
    const float* pb   = (const float*)d_in[5];
    const float* bt   = (const float*)d_in[6];
    const int*   ri   = (const int*)d_in[7];
    float* out = (float*)d_out;

    unsigned short* wqf = (unsigned short*)d_ws;
    unsigned short* wpf = wqf + 196608;
    unsigned short* bmf = (unsigned short*)((char*)d_ws + 524288);  // 4 MB

    const int nwin = in_sizes[0] / (NTOK * DIM);      // 4096
    const int total = 262144 + 64 * HEADS * 16 * 256; // 2359296

    k0_prep<<<(total + 255) / 256, 256, 0, stream>>>(qkvw, pw, mask, bt, ri,
                                                     wqf, wpf, bmf, total);
    k1_fused<<<nwin, 256, 0, stream>>>(x, qkvb, pb, wqf, wpf, bmf, out);
}

// Round 15
// 266.317 us; speedup vs baseline: 1.2162x; 1.2162x over previous
//
#include <hip/hip_runtime.h>
#include <hip/hip_bf16.h>

#define NTOK 49
#define DIM 256
#define HEADS 8
#define HD 32
#define SCALE 0.17677669529663687f

typedef float f32x4 __attribute__((ext_vector_type(4)));
typedef short bf16x8 __attribute__((ext_vector_type(8)));
typedef short bf16x4 __attribute__((ext_vector_type(4)));

__device__ __forceinline__ unsigned short f2bf(float f) {
    union { __hip_bfloat16 h; unsigned short u; } c;
    c.h = __float2bfloat16(f);
    return c.u;
}
__device__ __forceinline__ float bf2f(unsigned short u) {
    return __builtin_bit_cast(float, (unsigned)u << 16);
}
__device__ __forceinline__ uint2 pack4(float a, float b, float c, float d) {
    uint2 r;
    r.x = (unsigned)f2bf(a) | ((unsigned)f2bf(b) << 16);
    r.y = (unsigned)f2bf(c) | ((unsigned)f2bf(d) << 16);
    return r;
}

// K=16 bf16 MFMA on packed uint2 fragments (4 bf16/lane, k = (lane>>4)*4+j).
// Its A/B fragment layout coincides with the 16x16x32 D-fragment layout.
__device__ __forceinline__ f32x4 mfma16(uint2 a, uint2 b, f32x4 c) {
    bf16x4 av = __builtin_bit_cast(bf16x4, a);
    bf16x4 bv = __builtin_bit_cast(bf16x4, b);
#if __has_builtin(__builtin_amdgcn_mfma_f32_16x16x16bf16_1k)
    return __builtin_amdgcn_mfma_f32_16x16x16bf16_1k(av, bv, c, 0, 0, 0);
#elif __has_builtin(__builtin_amdgcn_mfma_f32_16x16x16_bf16)
    return __builtin_amdgcn_mfma_f32_16x16x16_bf16(av, bv, c, 0, 0, 0);
#else
    f32x4 d;
    asm volatile("v_mfma_f32_16x16x16_bf16 %0, %1, %2, %3"
                 : "=v"(d) : "v"(av), "v"(bv), "v"(c));
    return d;
#endif
}

// ---------------------------------------------------------------------------
// K0: one-time prep into d_ws (byte-identical to rounds 8/9/12/13):
//   wqf [196608] bf16 : qkv_w in MFMA fragment order
//   wpf [65536]  bf16 : proj_w in MFMA fragment order
//   bmf [2097152] bf16 : mask+bias in S^T D-fragment order
//       idx = ((ws*8+h)*16 + ct*4 + mt)*256 + lane*4 + j
//       -> (query q = ct*16 + (lane&15), key = mt*16 + (lane>>4)*4 + j)
// ---------------------------------------------------------------------------
__global__ void k0_prep(const float* __restrict__ qkv_w, const float* __restrict__ proj_w,
                        const float* __restrict__ mask, const float* __restrict__ bias_table,
                        const int* __restrict__ rel_idx,
                        unsigned short* __restrict__ wqf, unsigned short* __restrict__ wpf,
                        unsigned short* __restrict__ bmf, int total)
{
    int i = blockIdx.x * 256 + threadIdx.x;
    if (i >= total) return;
    if (i < 196608) {
        int j = i & 7, q = i >> 3;
        int lane = q & 63; q >>= 6;
        int ks2 = q & 7;  q >>= 3;
        int tt = q % 6;   q /= 6;
        int h  = q;
        int n96 = tt * 16 + (lane & 15);
        int seg = n96 >> 5, ch = n96 & 31;
        wqf[i] = f2bf(qkv_w[(seg * 256 + h * HD + ch) * 256 + ks2 * 32 + (lane >> 4) * 8 + j]);
    } else if (i < 262144) {
        int u = i - 196608;
        int j = u & 7, q = u >> 3;
        int lane = q & 63; q >>= 6;
        int ks2 = q & 7;  q >>= 3;
        int bt = q;                       // 0..15
        int n = (bt >> 3) * 128 + (bt & 7) * 16 + (lane & 15);
        wpf[u] = f2bf(proj_w[n * 256 + ks2 * 32 + (lane >> 4) * 8 + j]);
    } else {
        int u = i - 262144;               // [0, 2097152)
        int j = u & 3;
        int lane = (u >> 2) & 63;
        int g = u >> 8;                   // ws*128 + h*16 + ct*4 + mt
        int mt = g & 3, ct = (g >> 2) & 3, h = (g >> 4) & 7, ws = g >> 7;
        int q = ct * 16 + (lane & 15);
        int key = mt * 16 + ((lane >> 4) & 3) * 4 + j;
        float v = 0.f;
        if (q < NTOK && key < NTOK)
            v = mask[ws * 2401 + q * NTOK + key] + bias_table[rel_idx[q * NTOK + key] * HEADS + h];
        bmf[u] = f2bf(v);
    }
}

// ---------------------------------------------------------------------------
// K1: fully fused qkv + attention + proj. 4096 blocks x 512 threads (8 waves).
// ONE HEAD PER WAVE (h = wv); attention fully REGISTER-resident (q/k/v/P
// never touch LDS; 16x16x16 MFMAs consume 16x16x32 D-frags directly).
// Rationale (r4-r14 measurements): __launch_bounds__ 2nd arg a acts as
// {VGPR cap ~256/a, residency ~a blocks/CU}; our ~110-reg live set forces
// a=2, which with 4-wave blocks pinned us at 8 waves/CU (22.5% occ).
// 8-wave blocks at a=2 keep the 128-reg cap (zero spill) but double
// residency to 16 waves/CU. Per-head pipeline code is the verified r13 body;
// only the head->wave mapping, scatter ch0, and proj bt changed.
// Streaming x reads / out writes stay NON-TEMPORAL (keeps wqf/wpf/bmf L2-hot,
// r13: -25 MB FETCH, -22 us). 3 barriers/block.
// ---------------------------------------------------------------------------
__global__ __launch_bounds__(512, 2)
void k1_fused(
    const float* __restrict__ x,             // [4096,49,256] f32
    const float* __restrict__ qkv_b,         // [768] f32
    const float* __restrict__ pb,            // [256] f32
    const unsigned short* __restrict__ wqf,  // fragment-ordered qkv_w bf16
    const unsigned short* __restrict__ wpf,  // fragment-ordered proj_w bf16
    const unsigned short* __restrict__ bmf,  // fragment-ordered mask+bias bf16
    float* __restrict__ out)                 // [4096,49,256] f32 final
{
    __shared__ unsigned short xs[49 * 256];  // 25088 B (x; reused for ao)

    const int t = threadIdx.x, bw = blockIdx.x;
    const int lane = t & 63, wv = t >> 6;    // wv = head, 0..7
    const int l15 = lane & 15, l16 = lane >> 4;

    // ---- stage x rows 0..48 -> bf16 LDS (XOR swizzle; NON-TEMPORAL reads)
    const float* xw = x + (size_t)bw * NTOK * DIM;
    for (int cidx = t; cidx < NTOK * 32; cidx += 512) {
        int row = cidx >> 5, c8 = cidx & 31;
        f32x4 a = __builtin_nontemporal_load((const f32x4*)(xw + row * DIM + c8 * 8));
        f32x4 b = __builtin_nontemporal_load((const f32x4*)(xw + row * DIM + c8 * 8 + 4));
        bf16x8 v;
        v[0] = (short)f2bf(a[0]); v[1] = (short)f2bf(a[1]);
        v[2] = (short)f2bf(a[2]); v[3] = (short)f2bf(a[3]);
        v[4] = (short)f2bf(b[0]); v[5] = (short)f2bf(b[1]);
        v[6] = (short)f2bf(b[2]); v[7] = (short)f2bf(b[3]);
        *(bf16x8*)(xs + row * 256 + ((c8 * 8) ^ ((row & 7) << 3))) = v;
    }
    __syncthreads();   // barrier 1: xs ready

    int arow[4];
    #pragma unroll
    for (int i4 = 0; i4 < 4; ++i4) {
        int r = i4 * 16 + l15;
        arow[i4] = r > 48 ? 48 : r;     // row clamp (49 real rows in xs)
    }

    uint2 ob[2][4];                     // packed bf16 out^T frags [a][ct]

    const int h = wv;
    const unsigned short* wb = wqf + (size_t)h * 24576;
    uint2 qpk[4][2], kpk[4][2], vpk[4][2];   // [tok-tile][ch-chunk p]
    uint2 bmu[4][4];                         // [ct][mt] bias+mask frags

    // ---------- qkv: 2 passes of 16x16x32; outputs stay in registers ----
    #pragma unroll
    for (int p = 0; p < 2; ++p) {
        f32x4 aq[4], ak[4], av[4];
        #pragma unroll
        for (int nt = 0; nt < 4; ++nt) {
            aq[nt] = (f32x4){0.f,0.f,0.f,0.f};
            ak[nt] = (f32x4){0.f,0.f,0.f,0.f};
            av[nt] = (f32x4){0.f,0.f,0.f,0.f};
        }
        __builtin_amdgcn_s_setprio(1);
        #pragma unroll
        for (int ks2 = 0; ks2 < 8; ++ks2) {
            bf16x8 xf[4];
            #pragma unroll
            for (int nt = 0; nt < 4; ++nt)
                xf[nt] = *(const bf16x8*)(xs + arow[nt] * 256 +
                           ((ks2 * 32 + l16 * 8) ^ ((arow[nt] & 7) << 3)));
            bf16x8 wqf_ = *(const bf16x8*)(wb + ((p    ) * 8 + ks2) * 512 + lane * 8);
            bf16x8 wkf_ = *(const bf16x8*)(wb + ((2 + p) * 8 + ks2) * 512 + lane * 8);
            bf16x8 wvf_ = *(const bf16x8*)(wb + ((4 + p) * 8 + ks2) * 512 + lane * 8);
            #pragma unroll
            for (int nt = 0; nt < 4; ++nt) {
                aq[nt] = __builtin_amdgcn_mfma_f32_16x16x32_bf16(wqf_, xf[nt], aq[nt], 0, 0, 0);
                ak[nt] = __builtin_amdgcn_mfma_f32_16x16x32_bf16(wkf_, xf[nt], ak[nt], 0, 0, 0);
                av[nt] = __builtin_amdgcn_mfma_f32_16x16x32_bf16(xf[nt], wvf_, av[nt], 0, 0, 0);
            }
        }
        __builtin_amdgcn_s_setprio(0);

        if (p == 1) {   // prefetch softmax bias+mask (hidden by epilogue)
            #pragma unroll
            for (int ct = 0; ct < 4; ++ct)
                #pragma unroll
                for (int mt = 0; mt < 4; ++mt)
                    bmu[ct][mt] = *(const uint2*)(bmf +
                        (((size_t)(((bw & 63) * 8 + h) * 16 + ct * 4 + mt)) << 8) + (lane << 2));
        }

        // epilogue: bias + pack into MFMA-K16-ready register fragments
        float4 bq4 = *(const float4*)(qkv_b + h * HD + p * 16 + l16 * 4);
        float4 bk4 = *(const float4*)(qkv_b + 256 + h * HD + p * 16 + l16 * 4);
        float  bvs = qkv_b[512 + h * HD + p * 16 + l15];
        #pragma unroll
        for (int nt = 0; nt < 4; ++nt) {
            qpk[nt][p] = pack4((aq[nt][0] + bq4.x) * SCALE, (aq[nt][1] + bq4.y) * SCALE,
                               (aq[nt][2] + bq4.z) * SCALE, (aq[nt][3] + bq4.w) * SCALE);
            kpk[nt][p] = pack4(ak[nt][0] + bk4.x, ak[nt][1] + bk4.y,
                               ak[nt][2] + bk4.z, ak[nt][3] + bk4.w);
            vpk[nt][p] = pack4(av[nt][0] + bvs, av[nt][1] + bvs,
                               av[nt][2] + bvs, av[nt][3] + bvs);
        }
    }

    // ---------- per q-tile ct: S^T (reg) + softmax + PV (reg) ----------
    #pragma unroll
    for (int ct = 0; ct < 4; ++ct) {
        f32x4 sT[4];
        __builtin_amdgcn_s_setprio(1);
        #pragma unroll
        for (int mt = 0; mt < 4; ++mt) {
            f32x4 z = (f32x4){0.f,0.f,0.f,0.f};
            sT[mt] = mfma16(kpk[mt][1], qpk[ct][1],
                            mfma16(kpk[mt][0], qpk[ct][0], z));
        }
        __builtin_amdgcn_s_setprio(0);

        float vv[4][4];
        float mx = -1e30f;
        #pragma unroll
        for (int mt = 0; mt < 4; ++mt) {
            float b0 = bf2f((unsigned short)(bmu[ct][mt].x & 0xffff));
            float b1 = bf2f((unsigned short)(bmu[ct][mt].x >> 16));
            float b2 = bf2f((unsigned short)(bmu[ct][mt].y & 0xffff));
            float b3 = bf2f((unsigned short)(bmu[ct][mt].y >> 16));
            float bj[4] = {b0, b1, b2, b3};
            #pragma unroll
            for (int j = 0; j < 4; ++j) {
                float v = sT[mt][j] + bj[j];
                if (mt * 16 + l16 * 4 + j >= NTOK) v = -1e30f;  // key mask
                vv[mt][j] = v;
                mx = fmaxf(mx, v);
            }
        }
        mx = fmaxf(mx, __shfl_xor(mx, 16));
        mx = fmaxf(mx, __shfl_xor(mx, 32));
        float sum = 0.f;
        #pragma unroll
        for (int mt = 0; mt < 4; ++mt)
            #pragma unroll
            for (int j = 0; j < 4; ++j) {
                float e = __expf(vv[mt][j] - mx);
                vv[mt][j] = e;
                sum += e;
            }
        sum += __shfl_xor(sum, 16);
        sum += __shfl_xor(sum, 32);
        float inv = 1.f / sum;

        uint2 ppk[4];
        #pragma unroll
        for (int mt = 0; mt < 4; ++mt)
            ppk[mt] = pack4(vv[mt][0] * inv, vv[mt][1] * inv,
                            vv[mt][2] * inv, vv[mt][3] * inv);

        f32x4 o0 = (f32x4){0.f,0.f,0.f,0.f};
        f32x4 o1 = (f32x4){0.f,0.f,0.f,0.f};
        __builtin_amdgcn_s_setprio(1);
        #pragma unroll
        for (int mt = 0; mt < 4; ++mt) {
            o0 = mfma16(vpk[mt][0], ppk[mt], o0);
            o1 = mfma16(vpk[mt][1], ppk[mt], o1);
        }
        __builtin_amdgcn_s_setprio(0);
        ob[0][ct] = pack4(o0[0], o0[1], o0[2], o0[3]);
        ob[1][ct] = pack4(o1[0], o1[1], o1[2], o1[3]);
    }

    __syncthreads();   // barrier 2: all waves past their last xs read

    // ---- scatter this head's attention output into xs as bf16, b64 stores
    #pragma unroll
    for (int a = 0; a < 2; ++a) {
        #pragma unroll
        for (int ct = 0; ct < 4; ++ct) {
            int tok = ct * 16 + l15;
            if (tok < NTOK) {
                int ch0 = h * HD + a * 16 + l16 * 4;
                int ad = tok * 256 + ((ch0 & ~7) ^ ((tok & 7) << 3)) + (ch0 & 7);
                *(uint2*)(xs + ad) = ob[a][ct];
            }
        }
    }
    __syncthreads();   // barrier 3: ao ready in xs

    // ---- proj (swapped): D col=tok -> float4 NT stores. Wave: 2 col-tiles.
    f32x4 pacc[4][2];   // [ct][u]
    #pragma unroll
    for (int ct = 0; ct < 4; ++ct)
        #pragma unroll
        for (int u = 0; u < 2; ++u) pacc[ct][u] = (f32x4){0.f,0.f,0.f,0.f};

    __builtin_amdgcn_s_setprio(1);
    #pragma unroll
    for (int ks2 = 0; ks2 < 8; ++ks2) {
        bf16x8 xf[4];
        #pragma unroll
        for (int ct = 0; ct < 4; ++ct)
            xf[ct] = *(const bf16x8*)(xs + arow[ct] * 256 +
                       ((ks2 * 32 + l16 * 8) ^ ((arow[ct] & 7) << 3)));
        #pragma unroll
        for (int u = 0; u < 2; ++u) {
            bf16x8 wf = *(const bf16x8*)(wpf + (size_t)((wv * 2 + u) * 8 + ks2) * 512 + lane * 8);
            #pragma unroll
            for (int ct = 0; ct < 4; ++ct)
                pacc[ct][u] = __builtin_amdgcn_mfma_f32_16x16x32_bf16(wf, xf[ct], pacc[ct][u], 0, 0, 0);
        }
    }
    __builtin_amdgcn_s_setprio(0);

    #pragma unroll
    for (int u = 0; u < 2; ++u) {
        int bt = wv * 2 + u;
        int base = (bt >> 3) * 128 + (bt & 7) * 16;
        float4 pb4 = *(const float4*)(pb + base + l16 * 4);
        #pragma unroll
        for (int ct = 0; ct < 4; ++ct) {
            int tok = ct * 16 + l15;
            if (tok < NTOK) {
                f32x4 r;
                r[0] = pacc[ct][u][0] + pb4.x;
                r[1] = pacc[ct][u][1] + pb4.y;
                r[2] = pacc[ct][u][2] + pb4.z;
                r[3] = pacc[ct][u][3] + pb4.w;
                __builtin_nontemporal_store(r,
                    (f32x4*)(out + ((size_t)bw * NTOK + tok) * DIM + base + l16 * 4));
            }
        }
    }
}

extern "C" void kernel_launch(void* const* d_in, const int* in_sizes, int n_in,
                              void* d_out, int out_size, void* d_ws, size_t ws_size,
                              hipStream_t stream) {
    const float* x    = (const float*)d_in[0];
    const float* mask = (const float*)d_in[1];
    const float* qkvw = (const float*)d_in[2];
    const float* qkvb = (const float*)d_in[3];
    const float* pw   = (const float*)d_in[4];
    const float* pb   = (const float*)d_in[5];
    const float* bt   = (const float*)d_in[6];
    const int*   ri   = (const int*)d_in[7];
    float* out = (float*)d_out;

    unsigned short* wqf = (unsigned short*)d_ws;
    unsigned short* wpf = wqf + 196608;
    unsigned short* bmf = (unsigned short*)((char*)d_ws + 524288);  // 4 MB

    const int nwin = in_sizes[0] / (NTOK * DIM);      // 4096
    const int total = 262144 + 64 * HEADS * 16 * 256; // 2359296

    k0_prep<<<(total + 255) / 256, 256, 0, stream>>>(qkvw, pw, mask, bt, ri,
                                                     wqf, wpf, bmf, total);
    k1_fused<<<nwin, 512, 0, stream>>>(x, qkvb, pb, wqf, wpf, bmf, out);
}

// Round 16
// 224.412 us; speedup vs baseline: 1.4433x; 1.1867x over previous
//
#include <hip/hip_runtime.h>
#include <hip/hip_bf16.h>

#define NTOK 49
#define DIM 256
#define HEADS 8
#define HD 32
#define SCALE 0.17677669529663687f

typedef float f32x4 __attribute__((ext_vector_type(4)));
typedef short bf16x8 __attribute__((ext_vector_type(8)));
typedef short bf16x4 __attribute__((ext_vector_type(4)));

__device__ __forceinline__ unsigned short f2bf(float f) {
    union { __hip_bfloat16 h; unsigned short u; } c;
    c.h = __float2bfloat16(f);
    return c.u;
}
__device__ __forceinline__ float bf2f(unsigned short u) {
    return __builtin_bit_cast(float, (unsigned)u << 16);
}
__device__ __forceinline__ uint2 pack4(float a, float b, float c, float d) {
    uint2 r;
    r.x = (unsigned)f2bf(a) | ((unsigned)f2bf(b) << 16);
    r.y = (unsigned)f2bf(c) | ((unsigned)f2bf(d) << 16);
    return r;
}

// K=16 bf16 MFMA on packed uint2 fragments (4 bf16/lane, k = (lane>>4)*4+j).
// Its A/B fragment layout coincides with the 16x16x32 D-fragment layout.
__device__ __forceinline__ f32x4 mfma16(uint2 a, uint2 b, f32x4 c) {
    bf16x4 av = __builtin_bit_cast(bf16x4, a);
    bf16x4 bv = __builtin_bit_cast(bf16x4, b);
#if __has_builtin(__builtin_amdgcn_mfma_f32_16x16x16bf16_1k)
    return __builtin_amdgcn_mfma_f32_16x16x16bf16_1k(av, bv, c, 0, 0, 0);
#elif __has_builtin(__builtin_amdgcn_mfma_f32_16x16x16_bf16)
    return __builtin_amdgcn_mfma_f32_16x16x16_bf16(av, bv, c, 0, 0, 0);
#else
    f32x4 d;
    asm volatile("v_mfma_f32_16x16x16_bf16 %0, %1, %2, %3"
                 : "=v"(d) : "v"(av), "v"(bv), "v"(c));
    return d;
#endif
}

// ---------------------------------------------------------------------------
// K0: one-time prep into d_ws (byte-identical to rounds 8/9/12/13):
//   wqf [196608] bf16 : qkv_w in MFMA fragment order
//   wpf [65536]  bf16 : proj_w in MFMA fragment order
//   bmf [2097152] bf16 : mask+bias in S^T D-fragment order
//       idx = ((ws*8+h)*16 + ct*4 + mt)*256 + lane*4 + j
//       -> (query q = ct*16 + (lane&15), key = mt*16 + (lane>>4)*4 + j)
// ---------------------------------------------------------------------------
__global__ void k0_prep(const float* __restrict__ qkv_w, const float* __restrict__ proj_w,
                        const float* __restrict__ mask, const float* __restrict__ bias_table,
                        const int* __restrict__ rel_idx,
                        unsigned short* __restrict__ wqf, unsigned short* __restrict__ wpf,
                        unsigned short* __restrict__ bmf, int total)
{
    int i = blockIdx.x * 256 + threadIdx.x;
    if (i >= total) return;
    if (i < 196608) {
        int j = i & 7, q = i >> 3;
        int lane = q & 63; q >>= 6;
        int ks2 = q & 7;  q >>= 3;
        int tt = q % 6;   q /= 6;
        int h  = q;
        int n96 = tt * 16 + (lane & 15);
        int seg = n96 >> 5, ch = n96 & 31;
        wqf[i] = f2bf(qkv_w[(seg * 256 + h * HD + ch) * 256 + ks2 * 32 + (lane >> 4) * 8 + j]);
    } else if (i < 262144) {
        int u = i - 196608;
        int j = u & 7, q = u >> 3;
        int lane = q & 63; q >>= 6;
        int ks2 = q & 7;  q >>= 3;
        int bt = q;                       // 0..15
        int n = (bt >> 3) * 128 + (bt & 7) * 16 + (lane & 15);
        wpf[u] = f2bf(proj_w[n * 256 + ks2 * 32 + (lane >> 4) * 8 + j]);
    } else {
        int u = i - 262144;               // [0, 2097152)
        int j = u & 3;
        int lane = (u >> 2) & 63;
        int g = u >> 8;                   // ws*128 + h*16 + ct*4 + mt
        int mt = g & 3, ct = (g >> 2) & 3, h = (g >> 4) & 7, ws = g >> 7;
        int q = ct * 16 + (lane & 15);
        int key = mt * 16 + ((lane >> 4) & 3) * 4 + j;
        float v = 0.f;
        if (q < NTOK && key < NTOK)
            v = mask[ws * 2401 + q * NTOK + key] + bias_table[rel_idx[q * NTOK + key] * HEADS + h];
        bmf[u] = f2bf(v);
    }
}

// ---------------------------------------------------------------------------
// K1: fully fused qkv + attention + proj. 4096 blocks x 256 threads (4 waves).
// Wave wv owns heads {wv, wv+4}. Attention fully REGISTER-resident.
// r13 base (passed, 238us) with a REGISTER DIET to fit launch_bounds(256,3)'s
// ~85-VGPR cap without spill (r4-r15: arg a sets BOTH the VGPR cap ~256/a and
// residency ~a blocks/CU; r13's a=2 pinned us at 2 blocks/CU, 22.5% occ):
//   1. bmu bias+mask frags are TRANSIENT per q-tile (8 regs, loaded at the
//      top of each ct iteration, hidden under the S-MFMAs): -24 persistent.
//   2. attention output scatters to a dedicated aos LDS buffer right after
//      each head's PV (xs never overwritten): kills ob[16 regs] persistence
//      and one barrier. LDS 2x25088 = 50176 B -> 3 blocks/CU fits exactly.
// Streaming x reads / out writes stay NON-TEMPORAL. 2 barriers/block.
// ---------------------------------------------------------------------------
__global__ __launch_bounds__(256, 3)
void k1_fused(
    const float* __restrict__ x,             // [4096,49,256] f32
    const float* __restrict__ qkv_b,         // [768] f32
    const float* __restrict__ pb,            // [256] f32
    const unsigned short* __restrict__ wqf,  // fragment-ordered qkv_w bf16
    const unsigned short* __restrict__ wpf,  // fragment-ordered proj_w bf16
    const unsigned short* __restrict__ bmf,  // fragment-ordered mask+bias bf16
    float* __restrict__ out)                 // [4096,49,256] f32 final
{
    __shared__ unsigned short xs[49 * 256];   // 25088 B: x bf16, swizzled
    __shared__ unsigned short aos[49 * 256];  // 25088 B: attn-out bf16, swizzled

    const int t = threadIdx.x, bw = blockIdx.x;
    const int lane = t & 63, wv = t >> 6;
    const int l15 = lane & 15, l16 = lane >> 4;

    // ---- stage x rows 0..48 -> bf16 LDS (XOR swizzle; NON-TEMPORAL reads)
    const float* xw = x + (size_t)bw * NTOK * DIM;
    for (int cidx = t; cidx < NTOK * 32; cidx += 256) {
        int row = cidx >> 5, c8 = cidx & 31;
        f32x4 a = __builtin_nontemporal_load((const f32x4*)(xw + row * DIM + c8 * 8));
        f32x4 b = __builtin_nontemporal_load((const f32x4*)(xw + row * DIM + c8 * 8 + 4));
        bf16x8 v;
        v[0] = (short)f2bf(a[0]); v[1] = (short)f2bf(a[1]);
        v[2] = (short)f2bf(a[2]); v[3] = (short)f2bf(a[3]);
        v[4] = (short)f2bf(b[0]); v[5] = (short)f2bf(b[1]);
        v[6] = (short)f2bf(b[2]); v[7] = (short)f2bf(b[3]);
        *(bf16x8*)(xs + row * 256 + ((c8 * 8) ^ ((row & 7) << 3))) = v;
    }
    __syncthreads();   // barrier 1: xs ready

    int arow[4];
    #pragma unroll
    for (int i4 = 0; i4 < 4; ++i4) {
        int r = i4 * 16 + l15;
        arow[i4] = r > 48 ? 48 : r;     // row clamp (49 real rows)
    }

    #pragma unroll
    for (int hh = 0; hh < 2; ++hh) {
        const int h = wv + 4 * hh;
        const unsigned short* wb = wqf + (size_t)h * 24576;
        uint2 qpk[4][2], kpk[4][2], vpk[4][2];   // [tok-tile][ch-chunk p]

        // ---------- qkv: 2 passes of 16x16x32; outputs stay in registers ----
        #pragma unroll
        for (int p = 0; p < 2; ++p) {
            f32x4 aq[4], ak[4], av[4];
            #pragma unroll
            for (int nt = 0; nt < 4; ++nt) {
                aq[nt] = (f32x4){0.f,0.f,0.f,0.f};
                ak[nt] = (f32x4){0.f,0.f,0.f,0.f};
                av[nt] = (f32x4){0.f,0.f,0.f,0.f};
            }
            __builtin_amdgcn_s_setprio(1);
            #pragma unroll
            for (int ks2 = 0; ks2 < 8; ++ks2) {
                bf16x8 xf[4];
                #pragma unroll
                for (int nt = 0; nt < 4; ++nt)
                    xf[nt] = *(const bf16x8*)(xs + arow[nt] * 256 +
                               ((ks2 * 32 + l16 * 8) ^ ((arow[nt] & 7) << 3)));
                bf16x8 wqf_ = *(const bf16x8*)(wb + ((p    ) * 8 + ks2) * 512 + lane * 8);
                bf16x8 wkf_ = *(const bf16x8*)(wb + ((2 + p) * 8 + ks2) * 512 + lane * 8);
                bf16x8 wvf_ = *(const bf16x8*)(wb + ((4 + p) * 8 + ks2) * 512 + lane * 8);
                #pragma unroll
                for (int nt = 0; nt < 4; ++nt) {
                    aq[nt] = __builtin_amdgcn_mfma_f32_16x16x32_bf16(wqf_, xf[nt], aq[nt], 0, 0, 0);
                    ak[nt] = __builtin_amdgcn_mfma_f32_16x16x32_bf16(wkf_, xf[nt], ak[nt], 0, 0, 0);
                    av[nt] = __builtin_amdgcn_mfma_f32_16x16x32_bf16(xf[nt], wvf_, av[nt], 0, 0, 0);
                }
            }
            __builtin_amdgcn_s_setprio(0);

            // epilogue: bias + pack into MFMA-K16-ready register fragments
            float4 bq4 = *(const float4*)(qkv_b + h * HD + p * 16 + l16 * 4);
            float4 bk4 = *(const float4*)(qkv_b + 256 + h * HD + p * 16 + l16 * 4);
            float  bvs = qkv_b[512 + h * HD + p * 16 + l15];
            #pragma unroll
            for (int nt = 0; nt < 4; ++nt) {
                qpk[nt][p] = pack4((aq[nt][0] + bq4.x) * SCALE, (aq[nt][1] + bq4.y) * SCALE,
                                   (aq[nt][2] + bq4.z) * SCALE, (aq[nt][3] + bq4.w) * SCALE);
                kpk[nt][p] = pack4(ak[nt][0] + bk4.x, ak[nt][1] + bk4.y,
                                   ak[nt][2] + bk4.z, ak[nt][3] + bk4.w);
                vpk[nt][p] = pack4(av[nt][0] + bvs, av[nt][1] + bvs,
                                   av[nt][2] + bvs, av[nt][3] + bvs);
            }
        }

        // ---------- per q-tile ct: S^T (reg) + softmax + PV (reg) ----------
        #pragma unroll
        for (int ct = 0; ct < 4; ++ct) {
            // transient bias+mask frags; loads issue before the S-MFMAs
            uint2 bmu4[4];
            #pragma unroll
            for (int mt = 0; mt < 4; ++mt)
                bmu4[mt] = *(const uint2*)(bmf +
                    (((size_t)(((bw & 63) * 8 + h) * 16 + ct * 4 + mt)) << 8) + (lane << 2));

            f32x4 sT[4];
            __builtin_amdgcn_s_setprio(1);
            #pragma unroll
            for (int mt = 0; mt < 4; ++mt) {
                f32x4 z = (f32x4){0.f,0.f,0.f,0.f};
                sT[mt] = mfma16(kpk[mt][1], qpk[ct][1],
                                mfma16(kpk[mt][0], qpk[ct][0], z));
            }
            __builtin_amdgcn_s_setprio(0);

            float vv[4][4];
            float mx = -1e30f;
            #pragma unroll
            for (int mt = 0; mt < 4; ++mt) {
                float bj[4] = { bf2f((unsigned short)(bmu4[mt].x & 0xffff)),
                                bf2f((unsigned short)(bmu4[mt].x >> 16)),
                                bf2f((unsigned short)(bmu4[mt].y & 0xffff)),
                                bf2f((unsigned short)(bmu4[mt].y >> 16)) };
                #pragma unroll
                for (int j = 0; j < 4; ++j) {
                    float v = sT[mt][j] + bj[j];
                    if (mt * 16 + l16 * 4 + j >= NTOK) v = -1e30f;  // key mask
                    vv[mt][j] = v;
                    mx = fmaxf(mx, v);
                }
            }
            mx = fmaxf(mx, __shfl_xor(mx, 16));
            mx = fmaxf(mx, __shfl_xor(mx, 32));
            float sum = 0.f;
            #pragma unroll
            for (int mt = 0; mt < 4; ++mt)
                #pragma unroll
                for (int j = 0; j < 4; ++j) {
                    float e = __expf(vv[mt][j] - mx);
                    vv[mt][j] = e;
                    sum += e;
                }
            sum += __shfl_xor(sum, 16);
            sum += __shfl_xor(sum, 32);
            float inv = 1.f / sum;

            uint2 ppk[4];
            #pragma unroll
            for (int mt = 0; mt < 4; ++mt)
                ppk[mt] = pack4(vv[mt][0] * inv, vv[mt][1] * inv,
                                vv[mt][2] * inv, vv[mt][3] * inv);

            f32x4 o0 = (f32x4){0.f,0.f,0.f,0.f};
            f32x4 o1 = (f32x4){0.f,0.f,0.f,0.f};
            __builtin_amdgcn_s_setprio(1);
            #pragma unroll
            for (int mt = 0; mt < 4; ++mt) {
                o0 = mfma16(vpk[mt][0], ppk[mt], o0);
                o1 = mfma16(vpk[mt][1], ppk[mt], o1);
            }
            __builtin_amdgcn_s_setprio(0);

            // scatter this head's out^T frags straight to aos (xs untouched)
            int tok = ct * 16 + l15;
            if (tok < NTOK) {
                int ch0 = h * HD + l16 * 4;
                int ad0 = tok * 256 + ((ch0 & ~7) ^ ((tok & 7) << 3)) + (ch0 & 7);
                *(uint2*)(aos + ad0) = pack4(o0[0], o0[1], o0[2], o0[3]);
                int ch1 = h * HD + 16 + l16 * 4;
                int ad1 = tok * 256 + ((ch1 & ~7) ^ ((tok & 7) << 3)) + (ch1 & 7);
                *(uint2*)(aos + ad1) = pack4(o1[0], o1[1], o1[2], o1[3]);
            }
        }
    }

    __syncthreads();   // barrier 2: aos complete (all heads scattered)

    // ---- proj (swapped): D col=tok -> float4 NT stores. Wave: 4 col-tiles.
    f32x4 pacc[4][4];   // [ct][u]
    #pragma unroll
    for (int ct = 0; ct < 4; ++ct)
        #pragma unroll
        for (int u = 0; u < 4; ++u) pacc[ct][u] = (f32x4){0.f,0.f,0.f,0.f};

    __builtin_amdgcn_s_setprio(1);
    #pragma unroll
    for (int ks2 = 0; ks2 < 8; ++ks2) {
        bf16x8 xf[4];
        #pragma unroll
        for (int ct = 0; ct < 4; ++ct)
            xf[ct] = *(const bf16x8*)(aos + arow[ct] * 256 +
                       ((ks2 * 32 + l16 * 8) ^ ((arow[ct] & 7) << 3)));
        #pragma unroll
        for (int u = 0; u < 4; ++u) {
            bf16x8 wf = *(const bf16x8*)(wpf + (size_t)((wv * 4 + u) * 8 + ks2) * 512 + lane * 8);
            #pragma unroll
            for (int ct = 0; ct < 4; ++ct)
                pacc[ct][u] = __builtin_amdgcn_mfma_f32_16x16x32_bf16(wf, xf[ct], pacc[ct][u], 0, 0, 0);
        }
    }
    __builtin_amdgcn_s_setprio(0);

    #pragma unroll
    for (int u = 0; u < 4; ++u) {
        int bt = wv * 4 + u;
        int base = (bt >> 3) * 128 + (bt & 7) * 16;
        float4 pb4 = *(const float4*)(pb + base + l16 * 4);
        #pragma unroll
        for (int ct = 0; ct < 4; ++ct) {
            int tok = ct * 16 + l15;
            if (tok < NTOK) {
                f32x4 r;
                r[0] = pacc[ct][u][0] + pb4.x;
                r[1] = pacc[ct][u][1] + pb4.y;
                r[2] = pacc[ct][u][2] + pb4.z;
                r[3] = pacc[ct][u][3] + pb4.w;
                __builtin_nontemporal_store(r,
                    (f32x4*)(out + ((size_t)bw * NTOK + tok) * DIM + base + l16 * 4));
            }
        }
    }
}

extern "C" void kernel_launch(void* const* d_in, const int* in_sizes, int n_in,
                              void* d_out, int out_size, void* d_ws, size_t ws_size,
                              hipStream_t stream) {
    const float* x    = (const float*)d_in[0];
    const float* mask = (const float*)d_in[1];
    const float* qkvw = (const float*)d_in[2];
    const float* qkvb = (const float*)d_in[3];
    const float* pw   = (const float*)d_in[4];
    const float* pb   = (const float*)d_in[5];
    const float* bt   = (const float*)d_in[6];
    const int*   ri   = (const int*)d_in[7];
    float* out = (float*)d_out;

    unsigned short* wqf = (unsigned short*)d_ws;
    unsigned short* wpf = wqf + 196608;
    unsigned short* bmf = (unsigned short*)((char*)d_ws + 524288);  // 4 MB

    const int nwin = in_sizes[0] / (NTOK * DIM);      // 4096
    const int total = 262144 + 64 * HEADS * 16 * 256; // 2359296

    k0_prep<<<(total + 255) / 256, 256, 0, stream>>>(qkvw, pw, mask, bt, ri,
                                                     wqf, wpf, bmf, total);
    k1_fused<<<nwin, 256, 0, stream>>>(x, qkvb, pb, wqf, wpf, bmf, out);
}